// Round 10
// baseline (166.964 us; speedup 1.0000x reference)
//
#include <hip/hip_runtime.h>
#include <stdint.h>

#define NUM_HEADS 12
#define DH 64
#define SEQ 2048
#define BATCH 2
#define DM 768
#define NQK 1536  // Q cols [0,768) | K cols [768,1536)
#define LOG2E 1.44269504088896340736f

typedef short short8 __attribute__((ext_vector_type(8)));
typedef short short4_t __attribute__((ext_vector_type(4)));
typedef float f32x4 __attribute__((ext_vector_type(4)));

__device__ __forceinline__ short bf16_rne(float f) {
    union { float f; uint32_t u; } v; v.f = f;
    return (short)((v.u + 0x7FFFu + ((v.u >> 16) & 1u)) >> 16);
}

// ---------------- Kernel 0: prep (wt | xb), branch on blockIdx ----------------
__global__ __launch_bounds__(256) void prep_kernel(const float* __restrict__ Wq,
                                                   const float* __restrict__ Wk,
                                                   const float* __restrict__ x,
                                                   short* __restrict__ Wt,
                                                   short* __restrict__ Xb) {
    __shared__ float tile[32][33];
    const int bid = blockIdx.x;
    const int t = threadIdx.x;
    if (bid < 1152) {
        int n0 = (bid % 48) * 32;
        int k0 = (bid / 48) * 32;
        int tx = t & 31;
        int ty = t >> 5;
        const float* src = (n0 < DM) ? Wq : Wk;
        int nn0 = (n0 < DM) ? n0 : n0 - DM;
#pragma unroll
        for (int j = 0; j < 4; ++j) {
            int k = ty + 8 * j;
            tile[k][tx] = src[(size_t)(k0 + k) * DM + nn0 + tx];
        }
        __syncthreads();
#pragma unroll
        for (int j = 0; j < 4; ++j) {
            int n = ty + 8 * j;
            Wt[(size_t)(n0 + n) * DM + k0 + tx] = bf16_rne(tile[tx][n]);
        }
    } else {
        size_t base = (size_t)(bid - 1152) * 4096;
#pragma unroll
        for (int j = 0; j < 4; ++j) {
            size_t i = base + (size_t)(t + j * 256) * 4;
            f32x4 v = *(const f32x4*)(x + i);
            short4_t s;
#pragma unroll
            for (int e = 0; e < 4; ++e) s[e] = bf16_rne(v[e]);
            *(short4_t*)(Xb + i) = s;
        }
    }
}

// ---------------- Kernel 1: proj GEMM (blocks 0..383) + mpack (blocks 384..1407) ----------------
__global__ __launch_bounds__(256) void projm_kernel(const short* __restrict__ Xb,
                                                    const short* __restrict__ Wt,
                                                    const float* __restrict__ bq,
                                                    const float* __restrict__ bk,
                                                    const int* __restrict__ mask,
                                                    short* __restrict__ QK,
                                                    unsigned long long* __restrict__ Mb) {
    __shared__ short As[128 * 72];
    __shared__ short Bs[128 * 72];
    const int bid = blockIdx.x;
    const int t = threadIdx.x;
    if (bid >= 384) {
        // ---- mpack: 1024 blocks x 4 waves x 32 rows ----
        int wid = (bid - 384) * 4 + (t >> 6);
        int lane = t & 63;
        size_t base = (size_t)wid * 32;
        for (int i = 0; i < 32; ++i) {
            size_t w = base + i;
            int v = mask[w * 64 + lane];
            unsigned long long bal = __ballot(v != 0);
            if (lane == 0) Mb[w] = bal;
        }
        return;
    }
    const int m0 = (bid & 31) * 128;
    const int n0 = (bid >> 5) * 128;
    const int lane = t & 63;
    const int w = t >> 6;
    const int wr = w >> 1, wc = w & 1;
    const int lr = lane & 15;
    const int lk = lane >> 4;

    f32x4 acc[4][4] = {};

    for (int k0 = 0; k0 < DM; k0 += 64) {
#pragma unroll
        for (int j = 0; j < 4; ++j) {
            int idx = t + 256 * j;
            int row = idx >> 3;
            int ch = idx & 7;
            *(short8*)&As[row * 72 + ch * 8] =
                *(const short8*)&Xb[(size_t)(m0 + row) * DM + k0 + ch * 8];
            *(short8*)&Bs[row * 72 + ch * 8] =
                *(const short8*)&Wt[(size_t)(n0 + row) * DM + k0 + ch * 8];
        }
        __syncthreads();
#pragma unroll
        for (int kk = 0; kk < 2; ++kk) {
            short8 a[4], bfr[4];
#pragma unroll
            for (int m = 0; m < 4; ++m)
                a[m] = *(short8*)&As[(wr * 64 + m * 16 + lr) * 72 + kk * 32 + lk * 8];
#pragma unroll
            for (int n = 0; n < 4; ++n)
                bfr[n] = *(short8*)&Bs[(wc * 64 + n * 16 + lr) * 72 + kk * 32 + lk * 8];
#pragma unroll
            for (int m = 0; m < 4; ++m)
#pragma unroll
                for (int n = 0; n < 4; ++n)
                    acc[m][n] = __builtin_amdgcn_mfma_f32_16x16x32_bf16(a[m], bfr[n], acc[m][n], 0, 0, 0);
        }
        __syncthreads();
    }

    const int orow = m0 + wr * 64;
    const int ocol = n0 + wc * 64;
#pragma unroll
    for (int m = 0; m < 4; ++m) {
#pragma unroll
        for (int n = 0; n < 4; ++n) {
            int col = ocol + n * 16 + lr;
            float bias = (col < DM) ? bq[col] : bk[col - DM];
            float scale = (col < DM) ? 0.125f * LOG2E : 1.0f;
#pragma unroll
            for (int r = 0; r < 4; ++r) {
                int row = orow + m * 16 + lk * 4 + r;
                QK[(size_t)row * NQK + col] = bf16_rne((acc[m][n][r] + bias) * scale);
            }
        }
    }
}

// ---------------- Kernel 2: attn (R9 + T14 async-STAGE split) ----------------
__global__ __launch_bounds__(256) void attn_kernel(const short* __restrict__ QK,
                                                   const unsigned long long* __restrict__ Mb,
                                                   float* __restrict__ out) {
    __shared__ short Ks[2][64 * 72];   // 18.4 KB
    __shared__ float Pb[64 * 132];     // 33.8 KB
    const int bid = blockIdx.x;
    const int xcd = bid & 7;
    const int jj = bid >> 3;
    const int bh = xcd * 3 + (jj >> 5);
    const int qblk = jj & 31;
    const int b = bh / NUM_HEADS;
    const int h = bh % NUM_HEADS;
    const int t = threadIdx.x;
    const int lane = t & 63;
    const int w = t >> 6;
    const int lr = lane & 15;
    const int lk = lane >> 4;
    const int wq = qblk * 64 + w * 16;

    short8 aq[2];
#pragma unroll
    for (int ks = 0; ks < 2; ++ks)
        aq[ks] = *(const short8*)&QK[(size_t)(b * SEQ + wq + lr) * NQK + h * DH + ks * 32 + lk * 8];

    float lrow[4] = {0.f, 0.f, 0.f, 0.f};
    const size_t mrow0 = (size_t)b * SEQ * (SEQ / 64);
    const int srow = t >> 3, sch = t & 7;
    short8 rs0, rs1, rs2, rs3;

#define ATT_LOAD(KT)                                                                         \
    {                                                                                        \
        const short* kp =                                                                    \
            &QK[(size_t)(b * SEQ + (KT) + srow) * NQK + DM + h * DH + sch * 8];              \
        rs0 = *(const short8*)kp;                                                            \
        rs1 = *(const short8*)(kp + (size_t)32 * NQK);                                       \
        rs2 = *(const short8*)(kp + (size_t)64 * NQK);                                       \
        rs3 = *(const short8*)(kp + (size_t)96 * NQK);                                       \
    }

#define ATT_WRITE()                                                                          \
    {                                                                                        \
        *(short8*)&Ks[0][srow * 72 + sch * 8] = rs0;                                         \
        *(short8*)&Ks[0][(srow + 32) * 72 + sch * 8] = rs1;                                  \
        *(short8*)&Ks[1][srow * 72 + sch * 8] = rs2;                                         \
        *(short8*)&Ks[1][(srow + 32) * 72 + sch * 8] = rs3;                                  \
    }

    // ---- pass A: masked sum of exp2 (loads for g+1 issued before computing g) ----
    ATT_LOAD(0)
    ATT_WRITE()
    __syncthreads();
    for (int g = 0; g < 16; ++g) {
        const int kt = g * 128;
        if (g < 15) ATT_LOAD(kt + 128)
#pragma unroll
        for (int tb = 0; tb < 2; ++tb) {
            f32x4 sc[4];
#pragma unroll
            for (int nf = 0; nf < 4; ++nf) {
                short8 k0 = *(short8*)&Ks[tb][(nf * 16 + lr) * 72 + lk * 8];
                short8 k1 = *(short8*)&Ks[tb][(nf * 16 + lr) * 72 + 32 + lk * 8];
                f32x4 a = {0.f, 0.f, 0.f, 0.f};
                a = __builtin_amdgcn_mfma_f32_16x16x32_bf16(aq[0], k0, a, 0, 0, 0);
                a = __builtin_amdgcn_mfma_f32_16x16x32_bf16(aq[1], k1, a, 0, 0, 0);
                sc[nf] = a;
            }
#pragma unroll
            for (int r = 0; r < 4; ++r) {
                int q = wq + lk * 4 + r;
                unsigned long long mbs = Mb[mrow0 + (size_t)q * 32 + ((kt >> 6) + tb)] >> lr;
                float s = 0.f;
#pragma unroll
                for (int nf = 0; nf < 4; ++nf) {
                    float e = __builtin_amdgcn_exp2f(sc[nf][r]);
                    s += ((mbs >> (nf * 16)) & 1ull) ? e : 0.f;
                }
                lrow[r] += s;
            }
        }
        __syncthreads();
        if (g < 15) {
            ATT_WRITE()
        }
        __syncthreads();
    }

    // ---- reduce over the 16 key-lanes ----
    float inv[4];
#pragma unroll
    for (int r = 0; r < 4; ++r) {
        float l = lrow[r];
        l += __shfl_xor(l, 1, 64);
        l += __shfl_xor(l, 2, 64);
        l += __shfl_xor(l, 4, 64);
        l += __shfl_xor(l, 8, 64);
        inv[r] = 1.0f / l;
    }

    // ---- pass B: recompute -> Pb -> coalesced stores; loads for g+1 issued early ----
    const size_t obase0 = ((size_t)((b * NUM_HEADS + h) * SEQ) + qblk * 64) * SEQ;
    ATT_LOAD(0)
    ATT_WRITE()
    __syncthreads();
    for (int g = 0; g < 16; ++g) {
        const int kt = g * 128;
        if (g < 15) ATT_LOAD(kt + 128)
#pragma unroll
        for (int tb = 0; tb < 2; ++tb) {
            f32x4 sc[4];
#pragma unroll
            for (int nf = 0; nf < 4; ++nf) {
                short8 k0 = *(short8*)&Ks[tb][(nf * 16 + lr) * 72 + lk * 8];
                short8 k1 = *(short8*)&Ks[tb][(nf * 16 + lr) * 72 + 32 + lk * 8];
                f32x4 a = {0.f, 0.f, 0.f, 0.f};
                a = __builtin_amdgcn_mfma_f32_16x16x32_bf16(aq[0], k0, a, 0, 0, 0);
                a = __builtin_amdgcn_mfma_f32_16x16x32_bf16(aq[1], k1, a, 0, 0, 0);
                sc[nf] = a;
            }
#pragma unroll
            for (int r = 0; r < 4; ++r) {
                int q = wq + lk * 4 + r;
                int qloc = w * 16 + lk * 4 + r;
                unsigned long long mbs = Mb[mrow0 + (size_t)q * 32 + ((kt >> 6) + tb)] >> lr;
#pragma unroll
                for (int nf = 0; nf < 4; ++nf) {
                    float p = __builtin_amdgcn_exp2f(sc[nf][r]) * inv[r];
                    Pb[qloc * 132 + tb * 64 + nf * 16 + lr] =
                        ((mbs >> (nf * 16)) & 1ull) ? p : 0.f;
                }
            }
        }
        __syncthreads();  // Pb ready, Ks consumed
#pragma unroll
        for (int gg = 0; gg < 8; ++gg) {
            int row = gg * 8 + (t >> 5);
            int col = (t & 31) * 4;
            *(f32x4*)&out[obase0 + (size_t)row * SEQ + kt + col] = *(f32x4*)&Pb[row * 132 + col];
        }
        if (g < 15) {
            ATT_WRITE()
        }
        __syncthreads();  // Ks ready, Pb consumed
    }
#undef ATT_LOAD
#undef ATT_WRITE
}

extern "C" void kernel_launch(void* const* d_in, const int* in_sizes, int n_in,
                              void* d_out, int out_size, void* d_ws, size_t ws_size,
                              hipStream_t stream) {
    (void)in_sizes; (void)n_in; (void)out_size; (void)ws_size;
    const float* x = (const float*)d_in[0];
    const int* mask = (const int*)d_in[1];
    const float* Wq = (const float*)d_in[2];
    const float* bq = (const float*)d_in[3];
    const float* Wk = (const float*)d_in[4];
    const float* bk = (const float*)d_in[5];
    float* out = (float*)d_out;

    short* Wt = (short*)d_ws;                           // 1536*768 bf16
    short* Xb = Wt + (size_t)NQK * DM;                  // 4096*768 bf16
    short* QK = Xb + (size_t)BATCH * SEQ * DM;          // 4096*1536 bf16
    unsigned long long* Mb =
        (unsigned long long*)(QK + (size_t)BATCH * SEQ * NQK);  // 131072 u64

    prep_kernel<<<dim3(1920), 256, 0, stream>>>(Wq, Wk, x, Wt, Xb);
    projm_kernel<<<dim3(1408), 256, 0, stream>>>(Xb, Wt, bq, bk, mask, QK, Mb);
    attn_kernel<<<dim3(768), 256, 0, stream>>>(QK, Mb, out);
}

// Round 11
// 154.981 us; speedup vs baseline: 1.0773x; 1.0773x over previous
//
#include <hip/hip_runtime.h>
#include <stdint.h>

#define NUM_HEADS 12
#define DH 64
#define SEQ 2048
#define BATCH 2
#define DM 768
#define NQK 1536  // Q cols [0,768) | K cols [768,1536)
#define LOG2E 1.44269504088896340736f

typedef short short8 __attribute__((ext_vector_type(8)));
typedef short short4_t __attribute__((ext_vector_type(4)));
typedef float f32x4 __attribute__((ext_vector_type(4)));

__device__ __forceinline__ short bf16_rne(float f) {
    union { float f; uint32_t u; } v; v.f = f;
    return (short)((v.u + 0x7FFFu + ((v.u >> 16) & 1u)) >> 16);
}

// ---------------- Kernel 0: prep (wt | mpack), branch on blockIdx ----------------
__global__ __launch_bounds__(256) void prep_kernel(const float* __restrict__ Wq,
                                                   const float* __restrict__ Wk,
                                                   const int* __restrict__ mask,
                                                   short* __restrict__ Wt,
                                                   unsigned long long* __restrict__ Mb) {
    __shared__ float tile[32][33];
    const int bid = blockIdx.x;
    const int t = threadIdx.x;
    if (bid < 1152) {
        int n0 = (bid % 48) * 32;
        int k0 = (bid / 48) * 32;
        int tx = t & 31;
        int ty = t >> 5;
        const float* src = (n0 < DM) ? Wq : Wk;
        int nn0 = (n0 < DM) ? n0 : n0 - DM;
#pragma unroll
        for (int j = 0; j < 4; ++j) {
            int k = ty + 8 * j;
            tile[k][tx] = src[(size_t)(k0 + k) * DM + nn0 + tx];
        }
        __syncthreads();
#pragma unroll
        for (int j = 0; j < 4; ++j) {
            int n = ty + 8 * j;
            Wt[(size_t)(n0 + n) * DM + k0 + tx] = bf16_rne(tile[tx][n]);
        }
    } else {
        // ---- mpack ----
        int wid = (bid - 1152) * 4 + (t >> 6);
        int lane = t & 63;
        size_t base = (size_t)wid * 8;
#pragma unroll
        for (int i = 0; i < 8; ++i) {
            size_t w = base + i;
            int v = mask[w * 64 + lane];
            unsigned long long bal = __ballot(v != 0);
            if (lane == 0) Mb[w] = bal;
        }
    }
}

// ---------------- Kernel 1: projection GEMM (128x128, BK=64; A staged from f32 x) ----------------
__global__ __launch_bounds__(256) void proj_kernel(const float* __restrict__ x,
                                                   const short* __restrict__ Wt,
                                                   const float* __restrict__ bq,
                                                   const float* __restrict__ bk,
                                                   short* __restrict__ QK) {
    __shared__ short As[128 * 72];
    __shared__ short Bs[128 * 72];
    const int m0 = blockIdx.x * 128;
    const int n0 = blockIdx.y * 128;
    const int t = threadIdx.x;
    const int lane = t & 63;
    const int w = t >> 6;
    const int wr = w >> 1, wc = w & 1;
    const int lr = lane & 15;
    const int lk = lane >> 4;

    f32x4 acc[4][4] = {};

    for (int k0 = 0; k0 < DM; k0 += 64) {
#pragma unroll
        for (int j = 0; j < 4; ++j) {
            int idx = t + 256 * j;          // 0..1023
            int row = idx >> 3;             // 0..127
            int ch = idx & 7;               // 8 chunks of 8 elems = 64 k
            // A: load 8 f32 from x, convert to bf16 in-register (identical values to old Xb path)
            const float* xp = &x[(size_t)(m0 + row) * DM + k0 + ch * 8];
            f32x4 v0 = *(const f32x4*)xp;
            f32x4 v1 = *(const f32x4*)(xp + 4);
            short8 s;
#pragma unroll
            for (int e = 0; e < 4; ++e) { s[e] = bf16_rne(v0[e]); s[e + 4] = bf16_rne(v1[e]); }
            *(short8*)&As[row * 72 + ch * 8] = s;
            *(short8*)&Bs[row * 72 + ch * 8] =
                *(const short8*)&Wt[(size_t)(n0 + row) * DM + k0 + ch * 8];
        }
        __syncthreads();
#pragma unroll
        for (int kk = 0; kk < 2; ++kk) {
            short8 a[4], bfr[4];
#pragma unroll
            for (int m = 0; m < 4; ++m)
                a[m] = *(short8*)&As[(wr * 64 + m * 16 + lr) * 72 + kk * 32 + lk * 8];
#pragma unroll
            for (int n = 0; n < 4; ++n)
                bfr[n] = *(short8*)&Bs[(wc * 64 + n * 16 + lr) * 72 + kk * 32 + lk * 8];
#pragma unroll
            for (int m = 0; m < 4; ++m)
#pragma unroll
                for (int n = 0; n < 4; ++n)
                    acc[m][n] = __builtin_amdgcn_mfma_f32_16x16x32_bf16(a[m], bfr[n], acc[m][n], 0, 0, 0);
        }
        __syncthreads();
    }

    const int orow = m0 + wr * 64;
    const int ocol = n0 + wc * 64;
#pragma unroll
    for (int m = 0; m < 4; ++m) {
#pragma unroll
        for (int n = 0; n < 4; ++n) {
            int col = ocol + n * 16 + lr;
            float bias = (col < DM) ? bq[col] : bk[col - DM];
            float scale = (col < DM) ? 0.125f * LOG2E : 1.0f;
#pragma unroll
            for (int r = 0; r < 4; ++r) {
                int row = orow + m * 16 + lk * 4 + r;
                QK[(size_t)row * NQK + col] = bf16_rne((acc[m][n][r] + bias) * scale);
            }
        }
    }
}

// ---------------- Kernel 2: attn (R9: LDS store-transpose + XCD clustering) ----------------
__global__ __launch_bounds__(256) void attn_kernel(const short* __restrict__ QK,
                                                   const unsigned long long* __restrict__ Mb,
                                                   float* __restrict__ out) {
    __shared__ short Ks[2][64 * 72];   // 18.4 KB
    __shared__ float Pb[64 * 132];     // 33.8 KB
    const int bid = blockIdx.x;
    const int xcd = bid & 7;
    const int jj = bid >> 3;
    const int bh = xcd * 3 + (jj >> 5);
    const int qblk = jj & 31;
    const int b = bh / NUM_HEADS;
    const int h = bh % NUM_HEADS;
    const int t = threadIdx.x;
    const int lane = t & 63;
    const int w = t >> 6;
    const int lr = lane & 15;
    const int lk = lane >> 4;
    const int wq = qblk * 64 + w * 16;

    short8 aq[2];
#pragma unroll
    for (int ks = 0; ks < 2; ++ks)
        aq[ks] = *(const short8*)&QK[(size_t)(b * SEQ + wq + lr) * NQK + h * DH + ks * 32 + lk * 8];

    float lrow[4] = {0.f, 0.f, 0.f, 0.f};
    const size_t mrow0 = (size_t)b * SEQ * (SEQ / 64);
    const int srow = t >> 3, sch = t & 7;

#define ATT_STAGE(KT)                                                                             \
    {                                                                                             \
        _Pragma("unroll") for (int tb = 0; tb < 2; ++tb) {                                        \
            *(short8*)&Ks[tb][srow * 72 + sch * 8] =                                              \
                *(const short8*)&QK[(size_t)(b * SEQ + (KT) + tb * 64 + srow) * NQK + DM +        \
                                    h * DH + sch * 8];                                            \
            *(short8*)&Ks[tb][(srow + 32) * 72 + sch * 8] =                                       \
                *(const short8*)&QK[(size_t)(b * SEQ + (KT) + tb * 64 + srow + 32) * NQK + DM +   \
                                    h * DH + sch * 8];                                            \
        }                                                                                         \
    }

    // ---- pass A: masked sum of exp2 ----
    for (int kt = 0; kt < SEQ; kt += 128) {
        ATT_STAGE(kt)
        __syncthreads();
#pragma unroll
        for (int tb = 0; tb < 2; ++tb) {
            f32x4 sc[4];
#pragma unroll
            for (int nf = 0; nf < 4; ++nf) {
                short8 k0 = *(short8*)&Ks[tb][(nf * 16 + lr) * 72 + lk * 8];
                short8 k1 = *(short8*)&Ks[tb][(nf * 16 + lr) * 72 + 32 + lk * 8];
                f32x4 a = {0.f, 0.f, 0.f, 0.f};
                a = __builtin_amdgcn_mfma_f32_16x16x32_bf16(aq[0], k0, a, 0, 0, 0);
                a = __builtin_amdgcn_mfma_f32_16x16x32_bf16(aq[1], k1, a, 0, 0, 0);
                sc[nf] = a;
            }
#pragma unroll
            for (int r = 0; r < 4; ++r) {
                int q = wq + lk * 4 + r;
                unsigned long long mbs = Mb[mrow0 + (size_t)q * 32 + ((kt >> 6) + tb)] >> lr;
                float s = 0.f;
#pragma unroll
                for (int nf = 0; nf < 4; ++nf) {
                    float e = __builtin_amdgcn_exp2f(sc[nf][r]);
                    s += ((mbs >> (nf * 16)) & 1ull) ? e : 0.f;
                }
                lrow[r] += s;
            }
        }
        __syncthreads();
    }

    // ---- reduce over the 16 key-lanes ----
    float inv[4];
#pragma unroll
    for (int r = 0; r < 4; ++r) {
        float l = lrow[r];
        l += __shfl_xor(l, 1, 64);
        l += __shfl_xor(l, 2, 64);
        l += __shfl_xor(l, 4, 64);
        l += __shfl_xor(l, 8, 64);
        inv[r] = 1.0f / l;
    }

    // ---- pass B: recompute -> Pb (LDS) -> 512B-segment coalesced stores ----
    const size_t obase0 = ((size_t)((b * NUM_HEADS + h) * SEQ) + qblk * 64) * SEQ;
    for (int kt = 0; kt < SEQ; kt += 128) {
        ATT_STAGE(kt)
        __syncthreads();   // Ks ready; also fences previous group's Pb reads
#pragma unroll
        for (int tb = 0; tb < 2; ++tb) {
            f32x4 sc[4];
#pragma unroll
            for (int nf = 0; nf < 4; ++nf) {
                short8 k0 = *(short8*)&Ks[tb][(nf * 16 + lr) * 72 + lk * 8];
                short8 k1 = *(short8*)&Ks[tb][(nf * 16 + lr) * 72 + 32 + lk * 8];
                f32x4 a = {0.f, 0.f, 0.f, 0.f};
                a = __builtin_amdgcn_mfma_f32_16x16x32_bf16(aq[0], k0, a, 0, 0, 0);
                a = __builtin_amdgcn_mfma_f32_16x16x32_bf16(aq[1], k1, a, 0, 0, 0);
                sc[nf] = a;
            }
#pragma unroll
            for (int r = 0; r < 4; ++r) {
                int q = wq + lk * 4 + r;
                int qloc = w * 16 + lk * 4 + r;
                unsigned long long mbs = Mb[mrow0 + (size_t)q * 32 + ((kt >> 6) + tb)] >> lr;
#pragma unroll
                for (int nf = 0; nf < 4; ++nf) {
                    float p = __builtin_amdgcn_exp2f(sc[nf][r]) * inv[r];
                    Pb[qloc * 132 + tb * 64 + nf * 16 + lr] =
                        ((mbs >> (nf * 16)) & 1ull) ? p : 0.f;
                }
            }
        }
        __syncthreads();   // Pb ready
#pragma unroll
        for (int g = 0; g < 8; ++g) {
            int row = g * 8 + (t >> 5);
            int col = (t & 31) * 4;
            *(f32x4*)&out[obase0 + (size_t)row * SEQ + kt + col] = *(f32x4*)&Pb[row * 132 + col];
        }
    }
#undef ATT_STAGE
}

extern "C" void kernel_launch(void* const* d_in, const int* in_sizes, int n_in,
                              void* d_out, int out_size, void* d_ws, size_t ws_size,
                              hipStream_t stream) {
    (void)in_sizes; (void)n_in; (void)out_size; (void)ws_size;
    const float* x = (const float*)d_in[0];
    const int* mask = (const int*)d_in[1];
    const float* Wq = (const float*)d_in[2];
    const float* bq = (const float*)d_in[3];
    const float* Wk = (const float*)d_in[4];
    const float* bk = (const float*)d_in[5];
    float* out = (float*)d_out;

    short* Wt = (short*)d_ws;                           // 1536*768 bf16
    short* QK = Wt + (size_t)NQK * DM;                  // 4096*1536 bf16
    unsigned long long* Mb =
        (unsigned long long*)(QK + (size_t)BATCH * SEQ * NQK);  // 131072 u64

    prep_kernel<<<dim3(1152 + 4096), 256, 0, stream>>>(Wq, Wk, mask, Wt, Mb);
    proj_kernel<<<dim3(BATCH * SEQ / 128, NQK / 128), 256, 0, stream>>>(x, Wt, bq, bk, QK);
    attn_kernel<<<dim3(768), 256, 0, stream>>>(QK, Mb, out);
}